// Round 3
// baseline (399.834 us; speedup 1.0000x reference)
//
#include <hip/hip_runtime.h>

#define Bv 2
#define Tv 2048
#define Cv 2048
#define Hv 16
#define HKVv 4
#define HDv 128

typedef __attribute__((ext_vector_type(8))) __bf16 bf16x8;
typedef __attribute__((ext_vector_type(4))) float floatx4;

__device__ __forceinline__ unsigned short f2b(float f) {
  unsigned int x = __float_as_uint(f);
  x += 0x7fffu + ((x >> 16) & 1u);
  return (unsigned short)(x >> 16);
}

#define MFMA(a, b, c) __builtin_amdgcn_mfma_f32_16x16x32_bf16((a), (b), (c), 0, 0, 0)

// async global->LDS, 16B per lane; dest = wave-uniform base + lane*16
__device__ __forceinline__ void gld_lds16(const void* g, void* l) {
  __builtin_amdgcn_global_load_lds((const __attribute__((address_space(1))) void*)g,
                                   (__attribute__((address_space(3))) void*)l, 16, 0, 0);
}

// ---------------- fp32 -> bf16 contiguous cast ----------------
__global__ void cvt_kernel(const float* __restrict__ src, unsigned short* __restrict__ dst, int n4) {
  int i = blockIdx.x * blockDim.x + threadIdx.x;
  if (i < n4) {
    float4 f = ((const float4*)src)[i];
    ushort4 u;
    u.x = f2b(f.x); u.y = f2b(f.y); u.z = f2b(f.z); u.w = f2b(f.w);
    ((ushort4*)dst)[i] = u;
  }
}

// ---------------- transpose + cast: src (K x N) fp32 -> dst (N x K) bf16 ----------------
__global__ void tcvt_kernel(const float* __restrict__ src, unsigned short* __restrict__ dst, int K, int N) {
  __shared__ float tile[32][33];
  int k0 = blockIdx.x * 32, n0 = blockIdx.y * 32;
  int tx = threadIdx.x, ty = threadIdx.y;
  for (int i = ty; i < 32; i += 8)
    tile[i][tx] = src[(size_t)(k0 + i) * N + n0 + tx];
  __syncthreads();
  for (int i = ty; i < 32; i += 8)
    dst[(size_t)(n0 + i) * K + k0 + tx] = f2b(tile[tx][i]);
}

// ============ 3-slot counted-vmcnt GEMM (128M x 256N tile, BK=32, 8 waves) ============
// Sync structure (race-audited):
//   step t: vmcnt(3)  -> own stage(t) landed (only stage(t+1)'s 3 loads outstanding)
//           s_barrier -> ALL waves' stage(t) landed; all waves' ds_reads of tile t-1
//                        done (their lgkmcnt(0) preceded their barrier arrival)
//           stage(t+2) into slot (t+2)%3  (= tile t-1's slot, now safe to overwrite)
//           ds_read tile t frags; MFMA
// vmcnt never drains to 0 in the loop (T4); last step peeled with vmcnt(0).
// Per-thread stage loads/tile: A 1 + B 2 = 3  -> vmcnt(3).

#define STAGE3(sl, kk)                                             \
  do {                                                             \
    gld_lds16(gA + (kk) * 32, &Ash[sl][0] + sA * 8);               \
    gld_lds16(gB0 + (kk) * 32, &Bsh[sl][0] + sA * 8);              \
    gld_lds16(gB1 + (kk) * 32, &Bsh[sl][0] + sB1 * 8);             \
  } while (0)

__global__ __launch_bounds__(512, 2) void gemm_qkv(
    const unsigned short* __restrict__ xb,
    const unsigned short* __restrict__ wq_t,   // 2048 x 2048 (N-major)
    const unsigned short* __restrict__ wkv_t,  // 1024 x 2048 (N-major)
    const float* __restrict__ bq, const float* __restrict__ bkv,
    unsigned short* __restrict__ qs,   // (B,H,T,HD)
    unsigned short* __restrict__ ks,   // (B,HKV,T,HD)
    unsigned short* __restrict__ vs) { // (B,HKV,HD,T)
  __shared__ __align__(16) unsigned short Ash[3][128 * 32];
  __shared__ __align__(16) unsigned short Bsh[3][256 * 32];
  int tid = threadIdx.x;
  int wave = tid >> 6, lane = tid & 63;
  int c = lane & 15, quad = lane >> 4;
  int wr = (wave >> 2) * 64, wc = (wave & 3) * 64;  // 2M x 4N waves, 64x64 each
  int m0 = blockIdx.x * 128, n0 = blockIdx.y * 256;
  bool isq = (n0 < 2048);
  const unsigned short* wt = isq ? (wq_t + (size_t)n0 * 2048)
                                 : (wkv_t + (size_t)(n0 - 2048) * 2048);
  const unsigned short* Abase = xb + (size_t)m0 * 2048;

  floatx4 zero4 = {0.f, 0.f, 0.f, 0.f};
  floatx4 acc[4][4];
#pragma unroll
  for (int i = 0; i < 4; i++)
#pragma unroll
    for (int j = 0; j < 4; j++) acc[i][j] = zero4;

  // staging addresses: pre-swizzled global source, linear LDS dest (rule #21)
  int sA = tid, rA = sA >> 2, kcA = (sA & 3) ^ ((rA >> 1) & 3);
  int sB1 = tid + 512;
  int rB0 = tid >> 2, kcB0 = (tid & 3) ^ ((rB0 >> 1) & 3);
  int rB1 = sB1 >> 2, kcB1 = (sB1 & 3) ^ ((rB1 >> 1) & 3);
  const unsigned short* gA = Abase + (size_t)rA * 2048 + kcA * 8;
  const unsigned short* gB0 = wt + (size_t)rB0 * 2048 + kcB0 * 8;
  const unsigned short* gB1 = wt + (size_t)rB1 * 2048 + kcB1 * 8;
  int swz3 = quad ^ ((c >> 1) & 3);

  // prologue: 2 tiles in flight
  STAGE3(0, 0);
  STAGE3(1, 1);

  int cur = 0;
  for (int t = 0; t < 63; ++t) {
    asm volatile("s_waitcnt vmcnt(3)" ::: "memory");
    __builtin_amdgcn_s_barrier();
    int nx2 = cur + 2; if (nx2 >= 3) nx2 -= 3;
    if (t < 62) STAGE3(nx2, t + 2);
    bf16x8 af[4], bfv[4];
#pragma unroll
    for (int i = 0; i < 4; i++)
      af[i] = *(const bf16x8*)(&Ash[cur][(wr + i * 16 + c) * 32 + swz3 * 8]);
#pragma unroll
    for (int j = 0; j < 4; j++)
      bfv[j] = *(const bf16x8*)(&Bsh[cur][(wc + j * 16 + c) * 32 + swz3 * 8]);
#pragma unroll
    for (int i = 0; i < 4; i++)
#pragma unroll
      for (int j = 0; j < 4; j++)
        acc[i][j] = MFMA(af[i], bfv[j], acc[i][j]);
    cur = (cur == 2) ? 0 : cur + 1;
  }
  // peeled last step (t = 63, cur == 0): nothing left in flight to count past
  asm volatile("s_waitcnt vmcnt(0)" ::: "memory");
  __builtin_amdgcn_s_barrier();
  {
    bf16x8 af[4], bfv[4];
#pragma unroll
    for (int i = 0; i < 4; i++)
      af[i] = *(const bf16x8*)(&Ash[cur][(wr + i * 16 + c) * 32 + swz3 * 8]);
#pragma unroll
    for (int j = 0; j < 4; j++)
      bfv[j] = *(const bf16x8*)(&Bsh[cur][(wc + j * 16 + c) * 32 + swz3 * 8]);
#pragma unroll
    for (int i = 0; i < 4; i++)
#pragma unroll
      for (int j = 0; j < 4; j++)
        acc[i][j] = MFMA(af[i], bfv[j], acc[i][j]);
  }

#pragma unroll
  for (int i = 0; i < 4; i++) {
#pragma unroll
    for (int j = 0; j < 4; j++) {
#pragma unroll
      for (int r = 0; r < 4; r++) {
        int m = m0 + wr + i * 16 + quad * 4 + r;
        int n = n0 + wc + j * 16 + c;
        int bidx = m >> 11, t = m & 2047;
        float val = acc[i][j][r];
        if (isq) {
          val = (val + bq[n]) * 0.08838834764831845f;  // 1/sqrt(128)
          int hh = n >> 7, d = n & 127;
          qs[((size_t)((bidx * Hv + hh) * Tv) + t) * HDv + d] = f2b(val);
        } else {
          int n2 = n - 2048;
          val += bkv[n2];
          if (n2 < 512) {
            int hh = n2 >> 7, d = n2 & 127;
            ks[((size_t)((bidx * HKVv + hh) * Tv) + t) * HDv + d] = f2b(val);
          } else {
            int n3 = n2 - 512;
            int hh = n3 >> 7, d = n3 & 127;
            vs[((size_t)((bidx * HKVv + hh) * HDv) + d) * Tv + t] = f2b(val);
          }
        }
      }
    }
  }
}

// ---------------- causal flash attention v5 (reverted to R1 structure) ----------------
__global__ __launch_bounds__(256, 4) void attn_kernel(
    const unsigned short* __restrict__ qs,   // (B,H,T,HD), pre-scaled
    const unsigned short* __restrict__ ks,   // (B,HKV,T,HD)
    const unsigned short* __restrict__ vs,   // (B,HKV,HD,T)
    unsigned short* __restrict__ ys) {       // (B,T,C) bf16
  __shared__ __align__(16) unsigned short Ksh[2][32 * 128];  // [kv][d]
  __shared__ __align__(16) unsigned short Vsh[2][128 * 32];  // [d][kv]
  __shared__ __align__(16) unsigned short Psh[4][16 * 32];   // per-wave [q][kv]

  int x = blockIdx.x, h = blockIdx.y, b = blockIdx.z;
  int qt = (h & 8) ? (31 - x) : x;   // balance: CU-resident blocks pair qt + (31-qt)
  int hkv = h & (HKVv - 1);
  int tid = threadIdx.x;
  int wave = tid >> 6, lane = tid & 63;
  int c = lane & 15, quad = lane >> 4;
  int q0w = qt * 64 + wave * 16;
  int qrow = q0w + c;
  int swzK = c & 7, swzV = (c >> 1) & 3;

  const unsigned short* qptr = qs + ((size_t)((b * Hv + h) * Tv) + q0w) * HDv;
  const unsigned short* kbase = ks + (size_t)((b * HKVv + hkv) * Tv) * HDv;
  const unsigned short* vbase = vs + (size_t)((b * HKVv + hkv) * HDv) * Tv;

  bf16x8 qf[4];
#pragma unroll
  for (int kc = 0; kc < 4; kc++)
    qf[kc] = *(const bf16x8*)(qptr + (size_t)c * HDv + kc * 32 + quad * 8);

  floatx4 zero4 = {0.f, 0.f, 0.f, 0.f};
  floatx4 o[8];
#pragma unroll
  for (int dt = 0; dt < 8; dt++) o[dt] = zero4;
  float M = -1e30f, L = 0.f;

  unsigned short* Pw = &Psh[wave][0];

  int kOff[2], vOff[2];
#pragma unroll
  for (int i = 0; i < 2; i++) {
    int s = wave * 128 + i * 64 + lane;
    int rk = s >> 4, gk = (s & 15) ^ (rk & 7);
    kOff[i] = rk * 128 + gk * 8;
    int rv = s >> 2, gv = (s & 3) ^ ((rv >> 1) & 3);
    vOff[i] = rv * Tv + gv * 8;
  }
  int ldsBase = (wave * 128) * 8;  // shorts

  int ntiles = 2 * qt + 2;

#pragma unroll
  for (int i = 0; i < 2; i++) gld_lds16(kbase + kOff[i], &Ksh[0][0] + ldsBase + i * 512);
#pragma unroll
  for (int i = 0; i < 2; i++) gld_lds16(vbase + vOff[i], &Vsh[0][0] + ldsBase + i * 512);
  __syncthreads();

  for (int kt = 0; kt < ntiles; kt++) {
    int kv0 = kt * 32;
    int cur = kt & 1;
    if (kt + 1 < ntiles) {
      int kv1 = (kt + 1) * 32;
#pragma unroll
      for (int i = 0; i < 2; i++)
        gld_lds16(kbase + (size_t)kv1 * 128 + kOff[i], &Ksh[cur ^ 1][0] + ldsBase + i * 512);
#pragma unroll
      for (int i = 0; i < 2; i++)
        gld_lds16(vbase + kv1 + vOff[i], &Vsh[cur ^ 1][0] + ldsBase + i * 512);
    }

    if (kv0 <= q0w + 15) {   // wave-active
      const unsigned short* Kb = &Ksh[cur][0];
      const unsigned short* Vb = &Vsh[cur][0];
      floatx4 st[2] = {zero4, zero4};
#pragma unroll
      for (int kc = 0; kc < 4; kc++) {
#pragma unroll
        for (int sub = 0; sub < 2; sub++) {
          bf16x8 kf = *(const bf16x8*)(&Kb[(sub * 16 + c) * 128 + (((kc * 4 + quad) ^ swzK) * 8)]);
          st[sub] = MFMA(kf, qf[kc], st[sub]);
        }
      }
      if (kv0 + 31 > q0w) {
#pragma unroll
        for (int sub = 0; sub < 2; sub++) {
          int kvb = kv0 + sub * 16 + quad * 4;
#pragma unroll
          for (int r = 0; r < 4; r++)
            if (kvb + r > qrow) st[sub][r] = -1e30f;
        }
      }
      float mx = -1e30f;
#pragma unroll
      for (int sub = 0; sub < 2; sub++)
        mx = fmaxf(mx, fmaxf(fmaxf(st[sub][0], st[sub][1]), fmaxf(st[sub][2], st[sub][3])));
      mx = fmaxf(mx, __shfl_xor(mx, 16));
      mx = fmaxf(mx, __shfl_xor(mx, 32));
      // T13 defer-max: only rescale when the tile max meaningfully exceeds the
      // running max; otherwise keep M and let P be bounded by e^8 (fine in bf16).
      if (!__all(mx <= M + 8.0f)) {
        float Mn = fmaxf(M, mx);
        float al = __expf(M - Mn);
        M = Mn;
        L *= al;
#pragma unroll
        for (int dt = 0; dt < 8; dt++) o[dt] *= al;
      }
      float l = 0.f;
#pragma unroll
      for (int sub = 0; sub < 2; sub++) {
        float p0 = __expf(st[sub][0] - M);
        float p1 = __expf(st[sub][1] - M);
        float p2 = __expf(st[sub][2] - M);
        float p3 = __expf(st[sub][3] - M);
        l += (p0 + p1) + (p2 + p3);
        unsigned int lo = (unsigned int)f2b(p0) | ((unsigned int)f2b(p1) << 16);
        unsigned int hi = (unsigned int)f2b(p2) | ((unsigned int)f2b(p3) << 16);
        int g = (sub * 2 + (quad >> 1)) ^ swzV;
        *(uint2*)(&Pw[c * 32 + g * 8 + (quad & 1) * 4]) = make_uint2(lo, hi);
      }
      l += __shfl_xor(l, 16);
      l += __shfl_xor(l, 32);
      L += l;
      bf16x8 pf = *(const bf16x8*)(&Pw[c * 32 + ((quad ^ swzV) * 8)]);
#pragma unroll
      for (int dt = 0; dt < 8; dt++) {
        bf16x8 vf = *(const bf16x8*)(&Vb[(dt * 16 + c) * 32 + ((quad ^ swzV) * 8)]);
        o[dt] = MFMA(vf, pf, o[dt]);
      }
    }
    __syncthreads();   // drains prefetch (vmcnt) + orders buffer reuse
  }

  float Li = 1.0f / L;
  size_t rowbase = ((size_t)(b * Tv + qrow)) * Cv + h * HDv;
#pragma unroll
  for (int dt = 0; dt < 8; dt++) {
    unsigned int lo = (unsigned int)f2b(o[dt][0] * Li) | ((unsigned int)f2b(o[dt][1] * Li) << 16);
    unsigned int hi2 = (unsigned int)f2b(o[dt][2] * Li) | ((unsigned int)f2b(o[dt][3] * Li) << 16);
    *(uint2*)(&ys[rowbase + dt * 16 + quad * 4]) = make_uint2(lo, hi2);
  }
}

// ---------------- output projection: 3-slot counted-vmcnt, 128x256 tile ----------------
__global__ __launch_bounds__(512, 2) void gemm_proj(
    const unsigned short* __restrict__ ys,
    const unsigned short* __restrict__ wp_t,  // 2048 x 2048 (N-major)
    const float* __restrict__ bp,
    float* __restrict__ out) {
  __shared__ __align__(16) unsigned short Ash[3][128 * 32];
  __shared__ __align__(16) unsigned short Bsh[3][256 * 32];
  int tid = threadIdx.x;
  int wave = tid >> 6, lane = tid & 63;
  int c = lane & 15, quad = lane >> 4;
  int wr = (wave >> 2) * 64, wc = (wave & 3) * 64;
  int m0 = blockIdx.x * 128, n0 = blockIdx.y * 256;
  const unsigned short* Abase = ys + (size_t)m0 * 2048;
  const unsigned short* wt = wp_t + (size_t)n0 * 2048;

  floatx4 zero4 = {0.f, 0.f, 0.f, 0.f};
  floatx4 acc[4][4];
#pragma unroll
  for (int i = 0; i < 4; i++)
#pragma unroll
    for (int j = 0; j < 4; j++) acc[i][j] = zero4;

  int sA = tid, rA = sA >> 2, kcA = (sA & 3) ^ ((rA >> 1) & 3);
  int sB1 = tid + 512;
  int rB0 = tid >> 2, kcB0 = (tid & 3) ^ ((rB0 >> 1) & 3);
  int rB1 = sB1 >> 2, kcB1 = (sB1 & 3) ^ ((rB1 >> 1) & 3);
  const unsigned short* gA = Abase + (size_t)rA * 2048 + kcA * 8;
  const unsigned short* gB0 = wt + (size_t)rB0 * 2048 + kcB0 * 8;
  const unsigned short* gB1 = wt + (size_t)rB1 * 2048 + kcB1 * 8;
  int swz3 = quad ^ ((c >> 1) & 3);

  STAGE3(0, 0);
  STAGE3(1, 1);

  int cur = 0;
  for (int t = 0; t < 63; ++t) {
    asm volatile("s_waitcnt vmcnt(3)" ::: "memory");
    __builtin_amdgcn_s_barrier();
    int nx2 = cur + 2; if (nx2 >= 3) nx2 -= 3;
    if (t < 62) STAGE3(nx2, t + 2);
    bf16x8 af[4], bfv[4];
#pragma unroll
    for (int i = 0; i < 4; i++)
      af[i] = *(const bf16x8*)(&Ash[cur][(wr + i * 16 + c) * 32 + swz3 * 8]);
#pragma unroll
    for (int j = 0; j < 4; j++)
      bfv[j] = *(const bf16x8*)(&Bsh[cur][(wc + j * 16 + c) * 32 + swz3 * 8]);
#pragma unroll
    for (int i = 0; i < 4; i++)
#pragma unroll
      for (int j = 0; j < 4; j++)
        acc[i][j] = MFMA(af[i], bfv[j], acc[i][j]);
    cur = (cur == 2) ? 0 : cur + 1;
  }
  asm volatile("s_waitcnt vmcnt(0)" ::: "memory");
  __builtin_amdgcn_s_barrier();
  {
    bf16x8 af[4], bfv[4];
#pragma unroll
    for (int i = 0; i < 4; i++)
      af[i] = *(const bf16x8*)(&Ash[cur][(wr + i * 16 + c) * 32 + swz3 * 8]);
#pragma unroll
    for (int j = 0; j < 4; j++)
      bfv[j] = *(const bf16x8*)(&Bsh[cur][(wc + j * 16 + c) * 32 + swz3 * 8]);
#pragma unroll
    for (int i = 0; i < 4; i++)
#pragma unroll
      for (int j = 0; j < 4; j++)
        acc[i][j] = MFMA(af[i], bfv[j], acc[i][j]);
  }

#pragma unroll
  for (int i = 0; i < 4; i++) {
#pragma unroll
    for (int j = 0; j < 4; j++) {
#pragma unroll
      for (int r = 0; r < 4; r++) {
        int m = m0 + wr + i * 16 + quad * 4 + r;
        int n = n0 + wc + j * 16 + c;
        out[(size_t)m * 2048 + n] = acc[i][j][r] + bp[n];
      }
    }
  }
}

extern "C" void kernel_launch(void* const* d_in, const int* in_sizes, int n_in,
                              void* d_out, int out_size, void* d_ws, size_t ws_size,
                              hipStream_t stream) {
  (void)in_sizes; (void)n_in; (void)out_size; (void)ws_size;
  const float* x   = (const float*)d_in[0];
  const float* Wkv = (const float*)d_in[1];
  const float* bkv = (const float*)d_in[2];
  const float* Wq  = (const float*)d_in[3];
  const float* bq  = (const float*)d_in[4];
  const float* Wp  = (const float*)d_in[5];
  const float* bp  = (const float*)d_in[6];
  float* out = (float*)d_out;

  char* ws = (char*)d_ws;
  unsigned short* xb    = (unsigned short*)(ws + 0);          // 16.78 MB
  unsigned short* wq_t  = (unsigned short*)(ws + 16777216);   //  8.39 MB
  unsigned short* wkv_t = (unsigned short*)(ws + 25165824);   //  4.19 MB
  unsigned short* wp_t  = (unsigned short*)(ws + 29360128);   //  8.39 MB
  unsigned short* qs    = (unsigned short*)(ws + 37748736);   // 16.78 MB
  unsigned short* ks    = (unsigned short*)(ws + 54525952);   //  4.19 MB
  unsigned short* vs    = (unsigned short*)(ws + 58720256);   //  4.19 MB
  unsigned short* ysbuf = (unsigned short*)(ws + 62914560);   // 16.78 MB  (end 79.7 MB)

  cvt_kernel<<<8192, 256, 0, stream>>>(x, xb, 2097152);
  tcvt_kernel<<<dim3(64, 64), dim3(32, 8), 0, stream>>>(Wq, wq_t, 2048, 2048);
  tcvt_kernel<<<dim3(64, 32), dim3(32, 8), 0, stream>>>(Wkv, wkv_t, 2048, 1024);
  tcvt_kernel<<<dim3(64, 64), dim3(32, 8), 0, stream>>>(Wp, wp_t, 2048, 2048);
  gemm_qkv<<<dim3(32, 12), 512, 0, stream>>>(xb, wq_t, wkv_t, bq, bkv, qs, ks, vs);
  attn_kernel<<<dim3(32, 16, 2), 256, 0, stream>>>(qs, ks, vs, ysbuf);
  gemm_proj<<<dim3(32, 8), 512, 0, stream>>>(ysbuf, wp_t, bp, out);
}

// Round 4
// 367.675 us; speedup vs baseline: 1.0875x; 1.0875x over previous
//
#include <hip/hip_runtime.h>

#define Bv 2
#define Tv 2048
#define Cv 2048
#define Hv 16
#define HKVv 4
#define HDv 128

typedef __attribute__((ext_vector_type(8))) __bf16 bf16x8;
typedef __attribute__((ext_vector_type(4))) float floatx4;

__device__ __forceinline__ unsigned short f2b(float f) {
  unsigned int x = __float_as_uint(f);
  x += 0x7fffu + ((x >> 16) & 1u);
  return (unsigned short)(x >> 16);
}

#define MFMA(a, b, c) __builtin_amdgcn_mfma_f32_16x16x32_bf16((a), (b), (c), 0, 0, 0)

// async global->LDS, 16B per lane; dest = wave-uniform base + lane*16
__device__ __forceinline__ void gld_lds16(const void* g, void* l) {
  __builtin_amdgcn_global_load_lds((const __attribute__((address_space(1))) void*)g,
                                   (__attribute__((address_space(3))) void*)l, 16, 0, 0);
}

// ---------------- fused prologue: x cast + 3 weight transposes, ONE launch ----------------
// blocks [0,8192): fp32->bf16 cast of x (float4 granularity)
// blocks [8192,12288): Wq transpose; [12288,14336): Wkv; [14336,18432): Wp
__global__ __launch_bounds__(256) void prep_kernel(
    const float* __restrict__ x, unsigned short* __restrict__ xb,
    const float* __restrict__ Wq, unsigned short* __restrict__ wq_t,
    const float* __restrict__ Wkv, unsigned short* __restrict__ wkv_t,
    const float* __restrict__ Wp, unsigned short* __restrict__ wp_t) {
  __shared__ float tile[32][33];
  int bid = blockIdx.x, tid = threadIdx.x;
  if (bid < 8192) {
    int i = bid * 256 + tid;
    float4 f = ((const float4*)x)[i];
    ushort4 u;
    u.x = f2b(f.x); u.y = f2b(f.y); u.z = f2b(f.z); u.w = f2b(f.w);
    ((ushort4*)xb)[i] = u;
    return;
  }
  const float* src; unsigned short* dst; int N, idx;
  if (bid < 8192 + 4096)      { idx = bid - 8192;  src = Wq;  dst = wq_t;  N = 2048; }
  else if (bid < 8192 + 6144) { idx = bid - 12288; src = Wkv; dst = wkv_t; N = 1024; }
  else                        { idx = bid - 14336; src = Wp;  dst = wp_t;  N = 2048; }
  const int K = 2048;
  int k0 = (idx & 63) * 32, n0 = (idx >> 6) * 32;   // K/32 == 64 tiles in k for all three
  int tx = tid & 31, ty = tid >> 5;
  for (int i = ty; i < 32; i += 8)
    tile[i][tx] = src[(size_t)(k0 + i) * N + n0 + tx];
  __syncthreads();
  for (int i = ty; i < 32; i += 8)
    dst[(size_t)(n0 + i) * K + k0 + tx] = f2b(tile[tx][i]);
}

// ---------------- fused QKV GEMM: dbuf LDS + cross-barrier prefetch (R1-proven) ----------------
__global__ __launch_bounds__(256) void gemm_qkv(
    const unsigned short* __restrict__ xb,
    const unsigned short* __restrict__ wq_t,   // 2048 x 2048 (N-major)
    const unsigned short* __restrict__ wkv_t,  // 1024 x 2048 (N-major)
    const float* __restrict__ bq, const float* __restrict__ bkv,
    unsigned short* __restrict__ qs,   // (B,H,T,HD)
    unsigned short* __restrict__ ks,   // (B,HKV,T,HD)
    unsigned short* __restrict__ vs) { // (B,HKV,HD,T)
  __shared__ __align__(16) unsigned short Ash[2][128 * 32];
  __shared__ __align__(16) unsigned short Bsh[2][128 * 32];
  int tid = threadIdx.x;
  int wave = tid >> 6, lane = tid & 63;
  int c = lane & 15, quad = lane >> 4;
  int wr = (wave >> 1) * 64, wc = (wave & 1) * 64;
  int m0 = blockIdx.x * 128, n0 = blockIdx.y * 128;
  bool isq = (n0 < 2048);
  const unsigned short* wt = isq ? (wq_t + (size_t)n0 * 2048)
                                 : (wkv_t + (size_t)(n0 - 2048) * 2048);
  floatx4 zero4 = {0.f, 0.f, 0.f, 0.f};
  floatx4 acc[4][4];
#pragma unroll
  for (int i = 0; i < 4; i++)
#pragma unroll
    for (int j = 0; j < 4; j++) acc[i][j] = zero4;

  const unsigned short* Abase = xb + (size_t)m0 * 2048;
  int s0 = wave * 128 + lane, s1 = wave * 128 + 64 + lane;
  int r0 = s0 >> 2, kc0 = (s0 & 3) ^ ((r0 >> 1) & 3);
  int r1 = s1 >> 2, kc1 = (s1 & 3) ^ ((r1 >> 1) & 3);
  int swz3 = quad ^ ((c >> 1) & 3);
  int dA0 = (wave * 128) * 8, dA1 = (wave * 128 + 64) * 8;

  // prologue: prefetch K-step 0 into buffer 0
  gld_lds16(Abase + (size_t)r0 * 2048 + kc0 * 8, &Ash[0][0] + dA0);
  gld_lds16(Abase + (size_t)r1 * 2048 + kc1 * 8, &Ash[0][0] + dA1);
  gld_lds16(wt + (size_t)r0 * 2048 + kc0 * 8, &Bsh[0][0] + dA0);
  gld_lds16(wt + (size_t)r1 * 2048 + kc1 * 8, &Bsh[0][0] + dA1);
  __syncthreads();

  for (int it = 0; it < 64; it++) {
    int cur = it & 1;
    if (it + 1 < 64) {   // prefetch next K-step; in flight during MFMA below
      int k1 = (it + 1) * 32;
      gld_lds16(Abase + (size_t)r0 * 2048 + k1 + kc0 * 8, &Ash[cur ^ 1][0] + dA0);
      gld_lds16(Abase + (size_t)r1 * 2048 + k1 + kc1 * 8, &Ash[cur ^ 1][0] + dA1);
      gld_lds16(wt + (size_t)r0 * 2048 + k1 + kc0 * 8, &Bsh[cur ^ 1][0] + dA0);
      gld_lds16(wt + (size_t)r1 * 2048 + k1 + kc1 * 8, &Bsh[cur ^ 1][0] + dA1);
    }
    bf16x8 af[4], bfv[4];
#pragma unroll
    for (int i = 0; i < 4; i++)
      af[i] = *(const bf16x8*)(&Ash[cur][(wr + i * 16 + c) * 32 + swz3 * 8]);
#pragma unroll
    for (int j = 0; j < 4; j++)
      bfv[j] = *(const bf16x8*)(&Bsh[cur][(wc + j * 16 + c) * 32 + swz3 * 8]);
#pragma unroll
    for (int i = 0; i < 4; i++)
#pragma unroll
      for (int j = 0; j < 4; j++)
        acc[i][j] = MFMA(af[i], bfv[j], acc[i][j]);
    __syncthreads();   // drains prefetch (vmcnt) + protects buffer reuse
  }

#pragma unroll
  for (int i = 0; i < 4; i++) {
#pragma unroll
    for (int j = 0; j < 4; j++) {
#pragma unroll
      for (int r = 0; r < 4; r++) {
        int m = m0 + wr + i * 16 + quad * 4 + r;
        int n = n0 + wc + j * 16 + c;
        int bidx = m >> 11, t = m & 2047;
        float val = acc[i][j][r];
        if (isq) {
          val = (val + bq[n]) * 0.08838834764831845f;  // 1/sqrt(128)
          int hh = n >> 7, d = n & 127;
          qs[((size_t)((bidx * Hv + hh) * Tv) + t) * HDv + d] = f2b(val);
        } else {
          int n2 = n - 2048;
          val += bkv[n2];
          if (n2 < 512) {
            int hh = n2 >> 7, d = n2 & 127;
            ks[((size_t)((bidx * HKVv + hh) * Tv) + t) * HDv + d] = f2b(val);
          } else {
            int n3 = n2 - 512;
            int hh = n3 >> 7, d = n3 & 127;
            vs[((size_t)((bidx * HKVv + hh) * HDv) + d) * Tv + t] = f2b(val);
          }
        }
      }
    }
  }
}

// ---------------- causal flash attention v7: v5 + KV-locality XCD swizzle ----------------
// 1-D grid of 1024 blocks. id%8 selects the (b,hkv) group, so (assuming round-robin
// block->XCD dispatch) each XCD streams exactly ONE 1MB K/V pair -> L2-resident.
// Within a group, consecutive ids interleave mirrored qt pairs {k, 31-k} so
// co-resident blocks on a CU stay work-balanced (R1's pairing, made explicit).
__global__ __launch_bounds__(256, 4) void attn_kernel(
    const unsigned short* __restrict__ qs,   // (B,H,T,HD), pre-scaled
    const unsigned short* __restrict__ ks,   // (B,HKV,T,HD)
    const unsigned short* __restrict__ vs,   // (B,HKV,HD,T)
    unsigned short* __restrict__ ys) {       // (B,T,C) bf16
  __shared__ __align__(16) unsigned short Ksh[2][32 * 128];  // [kv][d]
  __shared__ __align__(16) unsigned short Vsh[2][128 * 32];  // [d][kv]
  __shared__ __align__(16) unsigned short Psh[4][16 * 32];   // per-wave [q][kv]

  int id = blockIdx.x;
  int g = id & 7, r = id >> 3;            // g: (b,hkv) group -> XCD; r: 0..127
  int t = r & 31, hh = r >> 5;            // t: qt index; hh: head-within-group
  int qt = (t & 1) ? (31 - (t >> 1)) : (t >> 1);   // bijective 0..31, pairs {k,31-k} adjacent
  int b = g >> 2, hkv = g & 3;
  int h = hh * 4 + hkv;                   // h & 3 == hkv
  int tid = threadIdx.x;
  int wave = tid >> 6, lane = tid & 63;
  int c = lane & 15, quad = lane >> 4;
  int q0w = qt * 64 + wave * 16;
  int qrow = q0w + c;
  int swzK = c & 7, swzV = (c >> 1) & 3;

  const unsigned short* qptr = qs + ((size_t)((b * Hv + h) * Tv) + q0w) * HDv;
  const unsigned short* kbase = ks + (size_t)((b * HKVv + hkv) * Tv) * HDv;
  const unsigned short* vbase = vs + (size_t)((b * HKVv + hkv) * HDv) * Tv;

  bf16x8 qf[4];
#pragma unroll
  for (int kc = 0; kc < 4; kc++)
    qf[kc] = *(const bf16x8*)(qptr + (size_t)c * HDv + kc * 32 + quad * 8);

  floatx4 zero4 = {0.f, 0.f, 0.f, 0.f};
  floatx4 o[8];
#pragma unroll
  for (int dt = 0; dt < 8; dt++) o[dt] = zero4;
  float M = -1e30f, L = 0.f;

  unsigned short* Pw = &Psh[wave][0];

  int kOff[2], vOff[2];
#pragma unroll
  for (int i = 0; i < 2; i++) {
    int s = wave * 128 + i * 64 + lane;
    int rk = s >> 4, gk = (s & 15) ^ (rk & 7);
    kOff[i] = rk * 128 + gk * 8;
    int rv = s >> 2, gv = (s & 3) ^ ((rv >> 1) & 3);
    vOff[i] = rv * Tv + gv * 8;
  }
  int ldsBase = (wave * 128) * 8;  // shorts

  int ntiles = 2 * qt + 2;

#pragma unroll
  for (int i = 0; i < 2; i++) gld_lds16(kbase + kOff[i], &Ksh[0][0] + ldsBase + i * 512);
#pragma unroll
  for (int i = 0; i < 2; i++) gld_lds16(vbase + vOff[i], &Vsh[0][0] + ldsBase + i * 512);
  __syncthreads();

  for (int kt = 0; kt < ntiles; kt++) {
    int kv0 = kt * 32;
    int cur = kt & 1;
    if (kt + 1 < ntiles) {
      int kv1 = (kt + 1) * 32;
#pragma unroll
      for (int i = 0; i < 2; i++)
        gld_lds16(kbase + (size_t)kv1 * 128 + kOff[i], &Ksh[cur ^ 1][0] + ldsBase + i * 512);
#pragma unroll
      for (int i = 0; i < 2; i++)
        gld_lds16(vbase + kv1 + vOff[i], &Vsh[cur ^ 1][0] + ldsBase + i * 512);
    }

    if (kv0 <= q0w + 15) {   // wave-active
      const unsigned short* Kb = &Ksh[cur][0];
      const unsigned short* Vb = &Vsh[cur][0];
      floatx4 st[2] = {zero4, zero4};
#pragma unroll
      for (int kc = 0; kc < 4; kc++) {
#pragma unroll
        for (int sub = 0; sub < 2; sub++) {
          bf16x8 kf = *(const bf16x8*)(&Kb[(sub * 16 + c) * 128 + (((kc * 4 + quad) ^ swzK) * 8)]);
          st[sub] = MFMA(kf, qf[kc], st[sub]);
        }
      }
      if (kv0 + 31 > q0w) {
#pragma unroll
        for (int sub = 0; sub < 2; sub++) {
          int kvb = kv0 + sub * 16 + quad * 4;
#pragma unroll
          for (int r2 = 0; r2 < 4; r2++)
            if (kvb + r2 > qrow) st[sub][r2] = -1e30f;
        }
      }
      float mx = -1e30f;
#pragma unroll
      for (int sub = 0; sub < 2; sub++)
        mx = fmaxf(mx, fmaxf(fmaxf(st[sub][0], st[sub][1]), fmaxf(st[sub][2], st[sub][3])));
      mx = fmaxf(mx, __shfl_xor(mx, 16));
      mx = fmaxf(mx, __shfl_xor(mx, 32));
      // T13 defer-max: only rescale when the tile max meaningfully exceeds the
      // running max; otherwise keep M and let P be bounded by e^8 (fine in bf16).
      if (!__all(mx <= M + 8.0f)) {
        float Mn = fmaxf(M, mx);
        float al = __expf(M - Mn);
        M = Mn;
        L *= al;
#pragma unroll
        for (int dt = 0; dt < 8; dt++) o[dt] *= al;
      }
      float l = 0.f;
#pragma unroll
      for (int sub = 0; sub < 2; sub++) {
        float p0 = __expf(st[sub][0] - M);
        float p1 = __expf(st[sub][1] - M);
        float p2 = __expf(st[sub][2] - M);
        float p3 = __expf(st[sub][3] - M);
        l += (p0 + p1) + (p2 + p3);
        unsigned int lo = (unsigned int)f2b(p0) | ((unsigned int)f2b(p1) << 16);
        unsigned int hi = (unsigned int)f2b(p2) | ((unsigned int)f2b(p3) << 16);
        int gg = (sub * 2 + (quad >> 1)) ^ swzV;
        *(uint2*)(&Pw[c * 32 + gg * 8 + (quad & 1) * 4]) = make_uint2(lo, hi);
      }
      l += __shfl_xor(l, 16);
      l += __shfl_xor(l, 32);
      L += l;
      bf16x8 pf = *(const bf16x8*)(&Pw[c * 32 + ((quad ^ swzV) * 8)]);
#pragma unroll
      for (int dt = 0; dt < 8; dt++) {
        bf16x8 vf = *(const bf16x8*)(&Vb[(dt * 16 + c) * 32 + ((quad ^ swzV) * 8)]);
        o[dt] = MFMA(vf, pf, o[dt]);
      }
    }
    __syncthreads();   // drains prefetch (vmcnt) + orders buffer reuse
  }

  float Li = 1.0f / L;
  size_t rowbase = ((size_t)(b * Tv + qrow)) * Cv + h * HDv;
#pragma unroll
  for (int dt = 0; dt < 8; dt++) {
    unsigned int lo = (unsigned int)f2b(o[dt][0] * Li) | ((unsigned int)f2b(o[dt][1] * Li) << 16);
    unsigned int hi2 = (unsigned int)f2b(o[dt][2] * Li) | ((unsigned int)f2b(o[dt][3] * Li) << 16);
    *(uint2*)(&ys[rowbase + dt * 16 + quad * 4]) = make_uint2(lo, hi2);
  }
}

// ---------------- output projection: dbuf LDS + cross-barrier prefetch (R1-proven) ----------------
__global__ __launch_bounds__(256) void gemm_proj(
    const unsigned short* __restrict__ ys,
    const unsigned short* __restrict__ wp_t,  // 2048 x 2048 (N-major)
    const float* __restrict__ bp,
    float* __restrict__ out) {
  __shared__ __align__(16) unsigned short Ash[2][128 * 32];
  __shared__ __align__(16) unsigned short Bsh[2][128 * 32];
  int tid = threadIdx.x;
  int wave = tid >> 6, lane = tid & 63;
  int c = lane & 15, quad = lane >> 4;
  int wr = (wave >> 1) * 64, wc = (wave & 1) * 64;
  int m0 = blockIdx.x * 128, n0 = blockIdx.y * 128;
  floatx4 zero4 = {0.f, 0.f, 0.f, 0.f};
  floatx4 acc[4][4];
#pragma unroll
  for (int i = 0; i < 4; i++)
#pragma unroll
    for (int j = 0; j < 4; j++) acc[i][j] = zero4;

  const unsigned short* Abase = ys + (size_t)m0 * 2048;
  const unsigned short* Bbase = wp_t + (size_t)n0 * 2048;
  int s0 = wave * 128 + lane, s1 = wave * 128 + 64 + lane;
  int r0 = s0 >> 2, kc0 = (s0 & 3) ^ ((r0 >> 1) & 3);
  int r1 = s1 >> 2, kc1 = (s1 & 3) ^ ((r1 >> 1) & 3);
  int swz3 = quad ^ ((c >> 1) & 3);
  int dA0 = (wave * 128) * 8, dA1 = (wave * 128 + 64) * 8;

  gld_lds16(Abase + (size_t)r0 * 2048 + kc0 * 8, &Ash[0][0] + dA0);
  gld_lds16(Abase + (size_t)r1 * 2048 + kc1 * 8, &Ash[0][0] + dA1);
  gld_lds16(Bbase + (size_t)r0 * 2048 + kc0 * 8, &Bsh[0][0] + dA0);
  gld_lds16(Bbase + (size_t)r1 * 2048 + kc1 * 8, &Bsh[0][0] + dA1);
  __syncthreads();

  for (int it = 0; it < 64; it++) {
    int cur = it & 1;
    if (it + 1 < 64) {
      int k1 = (it + 1) * 32;
      gld_lds16(Abase + (size_t)r0 * 2048 + k1 + kc0 * 8, &Ash[cur ^ 1][0] + dA0);
      gld_lds16(Abase + (size_t)r1 * 2048 + k1 + kc1 * 8, &Ash[cur ^ 1][0] + dA1);
      gld_lds16(Bbase + (size_t)r0 * 2048 + k1 + kc0 * 8, &Bsh[cur ^ 1][0] + dA0);
      gld_lds16(Bbase + (size_t)r1 * 2048 + k1 + kc1 * 8, &Bsh[cur ^ 1][0] + dA1);
    }
    bf16x8 af[4], bfv[4];
#pragma unroll
    for (int i = 0; i < 4; i++)
      af[i] = *(const bf16x8*)(&Ash[cur][(wr + i * 16 + c) * 32 + swz3 * 8]);
#pragma unroll
    for (int j = 0; j < 4; j++)
      bfv[j] = *(const bf16x8*)(&Bsh[cur][(wc + j * 16 + c) * 32 + swz3 * 8]);
#pragma unroll
    for (int i = 0; i < 4; i++)
#pragma unroll
      for (int j = 0; j < 4; j++)
        acc[i][j] = MFMA(af[i], bfv[j], acc[i][j]);
    __syncthreads();
  }

#pragma unroll
  for (int i = 0; i < 4; i++) {
#pragma unroll
    for (int j = 0; j < 4; j++) {
#pragma unroll
      for (int r = 0; r < 4; r++) {
        int m = m0 + wr + i * 16 + quad * 4 + r;
        int n = n0 + wc + j * 16 + c;
        out[(size_t)m * 2048 + n] = acc[i][j][r] + bp[n];
      }
    }
  }
}

extern "C" void kernel_launch(void* const* d_in, const int* in_sizes, int n_in,
                              void* d_out, int out_size, void* d_ws, size_t ws_size,
                              hipStream_t stream) {
  (void)in_sizes; (void)n_in; (void)out_size; (void)ws_size;
  const float* x   = (const float*)d_in[0];
  const float* Wkv = (const float*)d_in[1];
  const float* bkv = (const float*)d_in[2];
  const float* Wq  = (const float*)d_in[3];
  const float* bq  = (const float*)d_in[4];
  const float* Wp  = (const float*)d_in[5];
  const float* bp  = (const float*)d_in[6];
  float* out = (float*)d_out;

  char* ws = (char*)d_ws;
  unsigned short* xb    = (unsigned short*)(ws + 0);          // 16.78 MB
  unsigned short* wq_t  = (unsigned short*)(ws + 16777216);   //  8.39 MB
  unsigned short* wkv_t = (unsigned short*)(ws + 25165824);   //  4.19 MB
  unsigned short* wp_t  = (unsigned short*)(ws + 29360128);   //  8.39 MB
  unsigned short* qs    = (unsigned short*)(ws + 37748736);   // 16.78 MB
  unsigned short* ks    = (unsigned short*)(ws + 54525952);   //  4.19 MB
  unsigned short* vs    = (unsigned short*)(ws + 58720256);   //  4.19 MB
  unsigned short* ysbuf = (unsigned short*)(ws + 62914560);   // 16.78 MB  (end 79.7 MB)

  prep_kernel<<<18432, 256, 0, stream>>>(x, xb, Wq, wq_t, Wkv, wkv_t, Wp, wp_t);
  gemm_qkv<<<dim3(32, 24), 256, 0, stream>>>(xb, wq_t, wkv_t, bq, bkv, qs, ks, vs);
  attn_kernel<<<1024, 256, 0, stream>>>(qs, ks, vs, ysbuf);
  gemm_proj<<<dim3(32, 16), 256, 0, stream>>>(ysbuf, wp_t, bp, out);
}

// Round 5
// 340.786 us; speedup vs baseline: 1.1733x; 1.0789x over previous
//
#include <hip/hip_runtime.h>

#define Bv 2
#define Tv 2048
#define Cv 2048
#define Hv 16
#define HKVv 4
#define HDv 128

typedef __attribute__((ext_vector_type(8))) __bf16 bf16x8;
typedef __attribute__((ext_vector_type(4))) float floatx4;

__device__ __forceinline__ unsigned short f2b(float f) {
  unsigned int x = __float_as_uint(f);
  x += 0x7fffu + ((x >> 16) & 1u);
  return (unsigned short)(x >> 16);
}

#define MFMA(a, b, c) __builtin_amdgcn_mfma_f32_16x16x32_bf16((a), (b), (c), 0, 0, 0)

// async global->LDS, 16B per lane; dest = wave-uniform base + lane*16
__device__ __forceinline__ void gld_lds16(const void* g, void* l) {
  __builtin_amdgcn_global_load_lds((const __attribute__((address_space(1))) void*)g,
                                   (__attribute__((address_space(3))) void*)l, 16, 0, 0);
}

// ---------------- fused prologue: x cast + 3 weight transposes, ONE launch ----------------
__global__ __launch_bounds__(256) void prep_kernel(
    const float* __restrict__ x, unsigned short* __restrict__ xb,
    const float* __restrict__ Wq, unsigned short* __restrict__ wq_t,
    const float* __restrict__ Wkv, unsigned short* __restrict__ wkv_t,
    const float* __restrict__ Wp, unsigned short* __restrict__ wp_t) {
  __shared__ float tile[32][33];
  int bid = blockIdx.x, tid = threadIdx.x;
  if (bid < 8192) {
    int i = bid * 256 + tid;
    float4 f = ((const float4*)x)[i];
    ushort4 u;
    u.x = f2b(f.x); u.y = f2b(f.y); u.z = f2b(f.z); u.w = f2b(f.w);
    ((ushort4*)xb)[i] = u;
    return;
  }
  const float* src; unsigned short* dst; int N, idx;
  if (bid < 8192 + 4096)      { idx = bid - 8192;  src = Wq;  dst = wq_t;  N = 2048; }
  else if (bid < 8192 + 6144) { idx = bid - 12288; src = Wkv; dst = wkv_t; N = 1024; }
  else                        { idx = bid - 14336; src = Wp;  dst = wp_t;  N = 2048; }
  const int K = 2048;
  int k0 = (idx & 63) * 32, n0 = (idx >> 6) * 32;
  int tx = tid & 31, ty = tid >> 5;
  for (int i = ty; i < 32; i += 8)
    tile[i][tx] = src[(size_t)(k0 + i) * N + n0 + tx];
  __syncthreads();
  for (int i = ty; i < 32; i += 8)
    dst[(size_t)(n0 + i) * K + k0 + tx] = f2b(tile[tx][i]);
}

// ---------------- fused QKV GEMM: dbuf LDS + cross-barrier prefetch (R1-proven) ----------------
__global__ __launch_bounds__(256) void gemm_qkv(
    const unsigned short* __restrict__ xb,
    const unsigned short* __restrict__ wq_t,   // 2048 x 2048 (N-major)
    const unsigned short* __restrict__ wkv_t,  // 1024 x 2048 (N-major)
    const float* __restrict__ bq, const float* __restrict__ bkv,
    unsigned short* __restrict__ qs,   // (B,H,T,HD)
    unsigned short* __restrict__ ks,   // (B,HKV,T,HD)
    unsigned short* __restrict__ vs) { // (B,HKV,HD,T)
  __shared__ __align__(16) unsigned short Ash[2][128 * 32];
  __shared__ __align__(16) unsigned short Bsh[2][128 * 32];
  int tid = threadIdx.x;
  int wave = tid >> 6, lane = tid & 63;
  int c = lane & 15, quad = lane >> 4;
  int wr = (wave >> 1) * 64, wc = (wave & 1) * 64;
  int m0 = blockIdx.x * 128, n0 = blockIdx.y * 128;
  bool isq = (n0 < 2048);
  const unsigned short* wt = isq ? (wq_t + (size_t)n0 * 2048)
                                 : (wkv_t + (size_t)(n0 - 2048) * 2048);
  floatx4 zero4 = {0.f, 0.f, 0.f, 0.f};
  floatx4 acc[4][4];
#pragma unroll
  for (int i = 0; i < 4; i++)
#pragma unroll
    for (int j = 0; j < 4; j++) acc[i][j] = zero4;

  const unsigned short* Abase = xb + (size_t)m0 * 2048;
  int s0 = wave * 128 + lane, s1 = wave * 128 + 64 + lane;
  int r0 = s0 >> 2, kc0 = (s0 & 3) ^ ((r0 >> 1) & 3);
  int r1 = s1 >> 2, kc1 = (s1 & 3) ^ ((r1 >> 1) & 3);
  int swz3 = quad ^ ((c >> 1) & 3);
  int dA0 = (wave * 128) * 8, dA1 = (wave * 128 + 64) * 8;

  gld_lds16(Abase + (size_t)r0 * 2048 + kc0 * 8, &Ash[0][0] + dA0);
  gld_lds16(Abase + (size_t)r1 * 2048 + kc1 * 8, &Ash[0][0] + dA1);
  gld_lds16(wt + (size_t)r0 * 2048 + kc0 * 8, &Bsh[0][0] + dA0);
  gld_lds16(wt + (size_t)r1 * 2048 + kc1 * 8, &Bsh[0][0] + dA1);
  __syncthreads();

  for (int it = 0; it < 64; it++) {
    int cur = it & 1;
    if (it + 1 < 64) {
      int k1 = (it + 1) * 32;
      gld_lds16(Abase + (size_t)r0 * 2048 + k1 + kc0 * 8, &Ash[cur ^ 1][0] + dA0);
      gld_lds16(Abase + (size_t)r1 * 2048 + k1 + kc1 * 8, &Ash[cur ^ 1][0] + dA1);
      gld_lds16(wt + (size_t)r0 * 2048 + k1 + kc0 * 8, &Bsh[cur ^ 1][0] + dA0);
      gld_lds16(wt + (size_t)r1 * 2048 + k1 + kc1 * 8, &Bsh[cur ^ 1][0] + dA1);
    }
    bf16x8 af[4], bfv[4];
#pragma unroll
    for (int i = 0; i < 4; i++)
      af[i] = *(const bf16x8*)(&Ash[cur][(wr + i * 16 + c) * 32 + swz3 * 8]);
#pragma unroll
    for (int j = 0; j < 4; j++)
      bfv[j] = *(const bf16x8*)(&Bsh[cur][(wc + j * 16 + c) * 32 + swz3 * 8]);
#pragma unroll
    for (int i = 0; i < 4; i++)
#pragma unroll
      for (int j = 0; j < 4; j++)
        acc[i][j] = MFMA(af[i], bfv[j], acc[i][j]);
    __syncthreads();
  }

#pragma unroll
  for (int i = 0; i < 4; i++) {
#pragma unroll
    for (int j = 0; j < 4; j++) {
#pragma unroll
      for (int r = 0; r < 4; r++) {
        int m = m0 + wr + i * 16 + quad * 4 + r;
        int n = n0 + wc + j * 16 + c;
        int bidx = m >> 11, t = m & 2047;
        float val = acc[i][j][r];
        if (isq) {
          val = (val + bq[n]) * 0.08838834764831845f;  // 1/sqrt(128)
          int hh = n >> 7, d = n & 127;
          qs[((size_t)((bidx * Hv + hh) * Tv) + t) * HDv + d] = f2b(val);
        } else {
          int n2 = n - 2048;
          val += bkv[n2];
          if (n2 < 512) {
            int hh = n2 >> 7, d = n2 & 127;
            ks[((size_t)((bidx * HKVv + hh) * Tv) + t) * HDv + d] = f2b(val);
          } else {
            int n3 = n2 - 512;
            int hh = n3 >> 7, d = n3 & 127;
            vs[((size_t)((bidx * HKVv + hh) * HDv) + d) * Tv + t] = f2b(val);
          }
        }
      }
    }
  }
}

// ---------------- causal flash attention v8: R1 body + balanced KV-local swizzle ----------------
// Block->CU model (validated by R1/R4 evidence): XCD = id%8, then consecutive fill, so
// same-CU mates are ids {g+32c+8j, j=0..3} i.e. consecutive r=id>>3 quadruples.
// Map r = 8m+2n+e: hh=n, qt = e ? 31-m : m. Same-CU quads get {m,31-m} twice ->
// per-CU work sum == 136 (exactly balanced), and id%8 == (b,hkv) group -> each XCD
// streams ONE 1MB K/V pair (L2-resident; R4 measured FETCH 39.5->12.3 MB).
__global__ __launch_bounds__(256, 4) void attn_kernel(
    const unsigned short* __restrict__ qs,   // (B,H,T,HD), pre-scaled
    const unsigned short* __restrict__ ks,   // (B,HKV,T,HD)
    const unsigned short* __restrict__ vs,   // (B,HKV,HD,T)
    unsigned short* __restrict__ ys) {       // (B,T,C) bf16
  __shared__ __align__(16) unsigned short Ksh[2][32 * 128];  // [kv][d]
  __shared__ __align__(16) unsigned short Vsh[2][128 * 32];  // [d][kv]
  __shared__ __align__(16) unsigned short Psh[4][16 * 32];   // per-wave [q][kv]

  int id = blockIdx.x;
  int g = id & 7;            // (b,hkv) group -> one XCD
  int rid = id >> 3;         // 0..127
  int mm = rid >> 3;         // 0..15
  int nn = (rid >> 1) & 3;   // head-within-group
  int ee = rid & 1;
  int qt = ee ? (31 - mm) : mm;
  int b = g >> 2, hkv = g & 3;
  int h = nn * 4 + hkv;      // h & 3 == hkv
  int tid = threadIdx.x;
  int wave = tid >> 6, lane = tid & 63;
  int c = lane & 15, quad = lane >> 4;
  int q0w = qt * 64 + wave * 16;
  int qrow = q0w + c;
  int swzK = c & 7, swzV = (c >> 1) & 3;

  const unsigned short* qptr = qs + ((size_t)((b * Hv + h) * Tv) + q0w) * HDv;
  const unsigned short* kbase = ks + (size_t)((b * HKVv + hkv) * Tv) * HDv;
  const unsigned short* vbase = vs + (size_t)((b * HKVv + hkv) * HDv) * Tv;

  bf16x8 qf[4];
#pragma unroll
  for (int kc = 0; kc < 4; kc++)
    qf[kc] = *(const bf16x8*)(qptr + (size_t)c * HDv + kc * 32 + quad * 8);

  floatx4 zero4 = {0.f, 0.f, 0.f, 0.f};
  floatx4 o[8];
#pragma unroll
  for (int dt = 0; dt < 8; dt++) o[dt] = zero4;
  float M = -1e30f, L = 0.f;

  unsigned short* Pw = &Psh[wave][0];

  int kOff[2], vOff[2];
#pragma unroll
  for (int i = 0; i < 2; i++) {
    int s = wave * 128 + i * 64 + lane;
    int rk = s >> 4, gk = (s & 15) ^ (rk & 7);
    kOff[i] = rk * 128 + gk * 8;
    int rv = s >> 2, gv = (s & 3) ^ ((rv >> 1) & 3);
    vOff[i] = rv * Tv + gv * 8;
  }
  int ldsBase = (wave * 128) * 8;  // shorts

  int ntiles = 2 * qt + 2;

#pragma unroll
  for (int i = 0; i < 2; i++) gld_lds16(kbase + kOff[i], &Ksh[0][0] + ldsBase + i * 512);
#pragma unroll
  for (int i = 0; i < 2; i++) gld_lds16(vbase + vOff[i], &Vsh[0][0] + ldsBase + i * 512);
  __syncthreads();

  for (int kt = 0; kt < ntiles; kt++) {
    int kv0 = kt * 32;
    int cur = kt & 1;
    if (kt + 1 < ntiles) {
      int kv1 = (kt + 1) * 32;
#pragma unroll
      for (int i = 0; i < 2; i++)
        gld_lds16(kbase + (size_t)kv1 * 128 + kOff[i], &Ksh[cur ^ 1][0] + ldsBase + i * 512);
#pragma unroll
      for (int i = 0; i < 2; i++)
        gld_lds16(vbase + kv1 + vOff[i], &Vsh[cur ^ 1][0] + ldsBase + i * 512);
    }

    if (kv0 <= q0w + 15) {   // wave-active
      const unsigned short* Kb = &Ksh[cur][0];
      const unsigned short* Vb = &Vsh[cur][0];
      floatx4 st[2] = {zero4, zero4};
#pragma unroll
      for (int kc = 0; kc < 4; kc++) {
#pragma unroll
        for (int sub = 0; sub < 2; sub++) {
          bf16x8 kf = *(const bf16x8*)(&Kb[(sub * 16 + c) * 128 + (((kc * 4 + quad) ^ swzK) * 8)]);
          st[sub] = MFMA(kf, qf[kc], st[sub]);
        }
      }
      if (kv0 + 31 > q0w) {
#pragma unroll
        for (int sub = 0; sub < 2; sub++) {
          int kvb = kv0 + sub * 16 + quad * 4;
#pragma unroll
          for (int r2 = 0; r2 < 4; r2++)
            if (kvb + r2 > qrow) st[sub][r2] = -1e30f;
        }
      }
      float mx = -1e30f;
#pragma unroll
      for (int sub = 0; sub < 2; sub++)
        mx = fmaxf(mx, fmaxf(fmaxf(st[sub][0], st[sub][1]), fmaxf(st[sub][2], st[sub][3])));
      mx = fmaxf(mx, __shfl_xor(mx, 16));
      mx = fmaxf(mx, __shfl_xor(mx, 32));
      // T13 defer-max
      if (!__all(mx <= M + 8.0f)) {
        float Mn = fmaxf(M, mx);
        float al = __expf(M - Mn);
        M = Mn;
        L *= al;
#pragma unroll
        for (int dt = 0; dt < 8; dt++) o[dt] *= al;
      }
      float l = 0.f;
#pragma unroll
      for (int sub = 0; sub < 2; sub++) {
        float p0 = __expf(st[sub][0] - M);
        float p1 = __expf(st[sub][1] - M);
        float p2 = __expf(st[sub][2] - M);
        float p3 = __expf(st[sub][3] - M);
        l += (p0 + p1) + (p2 + p3);
        unsigned int lo = (unsigned int)f2b(p0) | ((unsigned int)f2b(p1) << 16);
        unsigned int hi = (unsigned int)f2b(p2) | ((unsigned int)f2b(p3) << 16);
        int gg = (sub * 2 + (quad >> 1)) ^ swzV;
        *(uint2*)(&Pw[c * 32 + gg * 8 + (quad & 1) * 4]) = make_uint2(lo, hi);
      }
      l += __shfl_xor(l, 16);
      l += __shfl_xor(l, 32);
      L += l;
      bf16x8 pf = *(const bf16x8*)(&Pw[c * 32 + ((quad ^ swzV) * 8)]);
#pragma unroll
      for (int dt = 0; dt < 8; dt++) {
        bf16x8 vf = *(const bf16x8*)(&Vb[(dt * 16 + c) * 32 + ((quad ^ swzV) * 8)]);
        o[dt] = MFMA(vf, pf, o[dt]);
      }
    }
    __syncthreads();   // drains prefetch (vmcnt) + orders buffer reuse
  }

  float Li = 1.0f / L;
  size_t rowbase = ((size_t)(b * Tv + qrow)) * Cv + h * HDv;
#pragma unroll
  for (int dt = 0; dt < 8; dt++) {
    unsigned int lo = (unsigned int)f2b(o[dt][0] * Li) | ((unsigned int)f2b(o[dt][1] * Li) << 16);
    unsigned int hi2 = (unsigned int)f2b(o[dt][2] * Li) | ((unsigned int)f2b(o[dt][3] * Li) << 16);
    *(uint2*)(&ys[rowbase + dt * 16 + quad * 4]) = make_uint2(lo, hi2);
  }
}

// ---------------- output projection: dbuf LDS + cross-barrier prefetch (R1-proven) ----------------
__global__ __launch_bounds__(256) void gemm_proj(
    const unsigned short* __restrict__ ys,
    const unsigned short* __restrict__ wp_t,  // 2048 x 2048 (N-major)
    const float* __restrict__ bp,
    float* __restrict__ out) {
  __shared__ __align__(16) unsigned short Ash[2][128 * 32];
  __shared__ __align__(16) unsigned short Bsh[2][128 * 32];
  int tid = threadIdx.x;
  int wave = tid >> 6, lane = tid & 63;
  int c = lane & 15, quad = lane >> 4;
  int wr = (wave >> 1) * 64, wc = (wave & 1) * 64;
  int m0 = blockIdx.x * 128, n0 = blockIdx.y * 128;
  floatx4 zero4 = {0.f, 0.f, 0.f, 0.f};
  floatx4 acc[4][4];
#pragma unroll
  for (int i = 0; i < 4; i++)
#pragma unroll
    for (int j = 0; j < 4; j++) acc[i][j] = zero4;

  const unsigned short* Abase = ys + (size_t)m0 * 2048;
  const unsigned short* Bbase = wp_t + (size_t)n0 * 2048;
  int s0 = wave * 128 + lane, s1 = wave * 128 + 64 + lane;
  int r0 = s0 >> 2, kc0 = (s0 & 3) ^ ((r0 >> 1) & 3);
  int r1 = s1 >> 2, kc1 = (s1 & 3) ^ ((r1 >> 1) & 3);
  int swz3 = quad ^ ((c >> 1) & 3);
  int dA0 = (wave * 128) * 8, dA1 = (wave * 128 + 64) * 8;

  gld_lds16(Abase + (size_t)r0 * 2048 + kc0 * 8, &Ash[0][0] + dA0);
  gld_lds16(Abase + (size_t)r1 * 2048 + kc1 * 8, &Ash[0][0] + dA1);
  gld_lds16(Bbase + (size_t)r0 * 2048 + kc0 * 8, &Bsh[0][0] + dA0);
  gld_lds16(Bbase + (size_t)r1 * 2048 + kc1 * 8, &Bsh[0][0] + dA1);
  __syncthreads();

  for (int it = 0; it < 64; it++) {
    int cur = it & 1;
    if (it + 1 < 64) {
      int k1 = (it + 1) * 32;
      gld_lds16(Abase + (size_t)r0 * 2048 + k1 + kc0 * 8, &Ash[cur ^ 1][0] + dA0);
      gld_lds16(Abase + (size_t)r1 * 2048 + k1 + kc1 * 8, &Ash[cur ^ 1][0] + dA1);
      gld_lds16(Bbase + (size_t)r0 * 2048 + k1 + kc0 * 8, &Bsh[cur ^ 1][0] + dA0);
      gld_lds16(Bbase + (size_t)r1 * 2048 + k1 + kc1 * 8, &Bsh[cur ^ 1][0] + dA1);
    }
    bf16x8 af[4], bfv[4];
#pragma unroll
    for (int i = 0; i < 4; i++)
      af[i] = *(const bf16x8*)(&Ash[cur][(wr + i * 16 + c) * 32 + swz3 * 8]);
#pragma unroll
    for (int j = 0; j < 4; j++)
      bfv[j] = *(const bf16x8*)(&Bsh[cur][(wc + j * 16 + c) * 32 + swz3 * 8]);
#pragma unroll
    for (int i = 0; i < 4; i++)
#pragma unroll
      for (int j = 0; j < 4; j++)
        acc[i][j] = MFMA(af[i], bfv[j], acc[i][j]);
    __syncthreads();
  }

#pragma unroll
  for (int i = 0; i < 4; i++) {
#pragma unroll
    for (int j = 0; j < 4; j++) {
#pragma unroll
      for (int r = 0; r < 4; r++) {
        int m = m0 + wr + i * 16 + quad * 4 + r;
        int n = n0 + wc + j * 16 + c;
        out[(size_t)m * 2048 + n] = acc[i][j][r] + bp[n];
      }
    }
  }
}

extern "C" void kernel_launch(void* const* d_in, const int* in_sizes, int n_in,
                              void* d_out, int out_size, void* d_ws, size_t ws_size,
                              hipStream_t stream) {
  (void)in_sizes; (void)n_in; (void)out_size; (void)ws_size;
  const float* x   = (const float*)d_in[0];
  const float* Wkv = (const float*)d_in[1];
  const float* bkv = (const float*)d_in[2];
  const float* Wq  = (const float*)d_in[3];
  const float* bq  = (const float*)d_in[4];
  const float* Wp  = (const float*)d_in[5];
  const float* bp  = (const float*)d_in[6];
  float* out = (float*)d_out;

  char* ws = (char*)d_ws;
  unsigned short* xb    = (unsigned short*)(ws + 0);          // 16.78 MB
  unsigned short* wq_t  = (unsigned short*)(ws + 16777216);   //  8.39 MB
  unsigned short* wkv_t = (unsigned short*)(ws + 25165824);   //  4.19 MB
  unsigned short* wp_t  = (unsigned short*)(ws + 29360128);   //  8.39 MB
  unsigned short* qs    = (unsigned short*)(ws + 37748736);   // 16.78 MB
  unsigned short* ks    = (unsigned short*)(ws + 54525952);   //  4.19 MB
  unsigned short* vs    = (unsigned short*)(ws + 58720256);   //  4.19 MB
  unsigned short* ysbuf = (unsigned short*)(ws + 62914560);   // 16.78 MB  (end 79.7 MB)

  prep_kernel<<<18432, 256, 0, stream>>>(x, xb, Wq, wq_t, Wkv, wkv_t, Wp, wp_t);
  gemm_qkv<<<dim3(32, 24), 256, 0, stream>>>(xb, wq_t, wkv_t, bq, bkv, qs, ks, vs);
  attn_kernel<<<1024, 256, 0, stream>>>(qs, ks, vs, ysbuf);
  gemm_proj<<<dim3(32, 16), 256, 0, stream>>>(ysbuf, wp_t, bp, out);
}